// Round 10
// baseline (88.184 us; speedup 1.0000x reference)
//
#include <hip/hip_runtime.h>
#include <hip/hip_fp16.h>

// *** PROBE ROUND ***  R9 code with synth inner compute repeated 16x
// (DCE-guarded). Purpose: surface synth in rocprof top-5 (fills mask it at
// ~40us) and solve dur_us = base + 15*synth1 for synth's true cost.
// Output is byte-identical to R9 (last rep writes the same values).
//
// SineSynth: B=4, S=1000 sines, F=256 frames, 32x linear upsample -> T=8192.
// Closed-form phase (REVOLUTIONS -> v_fract feeds v_sin_f32), two kernels
// (fence-fusion catastrophic on CDNA4 — R7).

#define FS_D 44100.0
#define S_TOTAL 1000
#define FRAMES 256
#define T_OUT 8192
#define BATCH 4
#define CH 8
#define NC 125      // CH*NC = S_TOTAL
#define REPEAT 16

typedef float f32x2 __attribute__((ext_vector_type(2)));

template <bool ATOMIC>
__global__ __launch_bounds__(1024, 8) void synth(
    const float* __restrict__ freq, const float* __restrict__ amp,
    const float* __restrict__ initp, __half* __restrict__ pdst,
    float* __restrict__ odst)
{
  __shared__ float4 coef_lds[CH][FRAMES + 1];  // (c1,c2,d1,a0p); col 256 = head
  __shared__ float  base_lds[CH][FRAMES + 4];  // col 256 = head frac

  const int bx    = blockIdx.x;
  const int b     = bx / NC;
  const int chunk = bx % NC;
  const int s0    = chunk * CH;
  const int tid   = threadIdx.x;
  const int lane  = tid & 63;
  const int w     = tid >> 6;      // 0..15

  const float invfs = (float)(1.0 / FS_D);

  // ---- stage coefficients (16 waves x 2 sweeps = 8 rows x 256 k) ----
  #pragma unroll
  for (int rr = 0; rr < 2; ++rr) {
    const int r  = rr * 4 + (w >> 2);
    const int kA = (w & 3) * 64 + lane;
    const int kA1 = (kA < FRAMES - 1) ? kA + 1 : kA;   // tail clamp: c2=d1=0
    const long long roff = (long long)(b * S_TOTAL + s0 + r) * FRAMES;
    const float fA  = freq[roff + kA];
    const float fA1 = freq[roff + kA1];
    const float aA  = amp[roff + kA];
    const float aA1 = amp[roff + kA1];
    const float c1  = fA * invfs;
    const float c2  = (fA1 - fA) * (invfs * (1.0f / 64.0f));
    const float d1  = (aA1 - aA) * (1.0f / 32.0f);
    const float a0p = fmaf(-0.5f, d1, aA);
    coef_lds[r][kA] = make_float4(c1, c2, d1, a0p);
    if (kA == 0) coef_lds[r][FRAMES] = make_float4(c1, 0.f, 0.f, aA);  // head
  }

  // ---- per-row exclusive scan (double), waves 0..7, one row each ----
  if (w < 8) {
    const int r = w;
    const double inv2pi = 0.15915494309189535;
    const double k16    = 16.0 / FS_D;
    const long long roff = (long long)(b * S_TOTAL + s0 + r) * FRAMES;
    const float4 fv = reinterpret_cast<const float4*>(freq + roff)[lane];
    const double f0 = fv.x, f1 = fv.y, f2 = fv.z, f3 = fv.w;
    const double tot = f0 + f1 + f2 + f3;
    double incl = tot;
    #pragma unroll
    for (int off = 1; off < 64; off <<= 1) {
      double v = __shfl_up(incl, (unsigned)off, 64);
      if (lane >= off) incl += v;
    }
    double C = incl - tot;  // exclusive prefix of frames at 4*lane
    const double initrev = (double)initp[b * S_TOTAL + s0 + r] * inv2pi;
    if (lane == 0) base_lds[r][FRAMES] = (float)(initrev - floor(initrev));
    const double fk[4] = {f0, f1, f2, f3};
    float4 bw;
    #pragma unroll
    for (int i = 0; i < 4; ++i) {
      const double basev = k16 * (2.0 * C + fk[i]) + initrev;
      (&bw.x)[i] = (float)(basev - floor(basev));
      C += fk[i];
    }
    *reinterpret_cast<float4*>(&base_lds[r][4 * lane]) = bw;  // aligned b128
  }
  __syncthreads();

  // ---- synth: thread = (k=(w>>2)*64+lane, quarter q=w&3), 8 samples ----
  const int q = w & 3;
  const int k = (w >> 2) * 64 + lane;      // 0..255
  const bool hd = (k == FRAMES - 1) && (q >= 2);   // head t=0..15
  const int kidx = hd ? FRAMES : k;
  const int qq = hd ? (q - 2) : q;
  const int j0 = qq * 8;
  const int t0 = hd ? j0 : (k * 32 + 16 + j0);

  f32x2 u2[4];
  const float u0f = (float)(j0 + 1);
  #pragma unroll
  for (int h = 0; h < 4; ++h)
    u2[h] = (f32x2){u0f + (float)(2 * h), u0f + (float)(2 * h + 1)};

  f32x2 acc2[4];
  #pragma unroll
  for (int h = 0; h < 4; ++h) acc2[h] = (f32x2)(0.f);

  #pragma unroll 1
  for (int rep = 0; rep < REPEAT; ++rep) {
    #pragma unroll
    for (int r = 0; r < CH; ++r) {
      const float4 cf = coef_lds[r][kidx];
      const float  bs = base_lds[r][kidx];
      const f32x2 c1v = (f32x2)(cf.x);
      const f32x2 c2v = (f32x2)(cf.y);
      const f32x2 d1v = (f32x2)(cf.z);
      const f32x2 a0v = (f32x2)(cf.w);
      const f32x2 bsv = (f32x2)(bs);
      #pragma unroll
      for (int h = 0; h < 4; ++h) {
        const f32x2 t  = __builtin_elementwise_fma(c2v, u2[h], c1v);   // pk_fma
        const f32x2 p2 = __builtin_elementwise_fma(t, u2[h], bsv);     // pk_fma
        const f32x2 am = __builtin_elementwise_fma(d1v, u2[h], a0v);   // pk_fma
        f32x2 s2;
        s2.x = __builtin_amdgcn_sinf(__builtin_amdgcn_fractf(p2.x));
        s2.y = __builtin_amdgcn_sinf(__builtin_amdgcn_fractf(p2.y));
        acc2[h] = __builtin_elementwise_fma(am, s2, acc2[h]);          // pk_fma
      }
    }
    if (rep != REPEAT - 1) {
      // DCE guard (rule #17): consume acc via empty asm, then re-zero.
      #pragma unroll
      for (int h = 0; h < 4; ++h) {
        float ax = acc2[h].x, ay = acc2[h].y;
        asm volatile("" : "+v"(ax), "+v"(ay));
        acc2[h] = (f32x2)(0.f);
      }
    }
  }

  // ---- write-out ----
  if (ATOMIC) {
    float* outb = odst + (long long)b * T_OUT + t0;
    #pragma unroll
    for (int h = 0; h < 4; ++h) {
      atomicAdd(outb + 2 * h,     acc2[h].x);
      atomicAdd(outb + 2 * h + 1, acc2[h].y);
    }
  } else {
    __half* pout = pdst + (size_t)(b * NC + chunk) * T_OUT + t0;
    union { float4 f; __half2 h[4]; } u;
    u.h[0] = __floats2half2_rn(acc2[0].x, acc2[0].y);
    u.h[1] = __floats2half2_rn(acc2[1].x, acc2[1].y);
    u.h[2] = __floats2half2_rn(acc2[2].x, acc2[2].y);
    u.h[3] = __floats2half2_rn(acc2[3].x, acc2[3].y);
    *reinterpret_cast<float4*>(pout) = u.f;
  }
}

// Reduce: 256 blocks x 256 thr. Column = 8 output samples (16B of fp16).
__global__ __launch_bounds__(256) void reduce_out(
    const __half* __restrict__ partial, float* __restrict__ out)
{
  __shared__ float red[16][16][8];
  const int tid = threadIdx.x;
  const int col = tid & 15;               // 0..15 within block
  const int g   = tid >> 4;               // 0..15 chunk-group
  const int bx  = blockIdx.x;             // 0..255
  const int b   = bx >> 6;                // 64 blocks per batch
  const int cb  = (bx & 63) * 16 + col;   // column in batch, 0..1023
  const __half* pbase = partial + (size_t)b * NC * T_OUT + (size_t)cb * 8;

  f32x2 s2[4];
  #pragma unroll
  for (int i = 0; i < 4; ++i) s2[i] = (f32x2)(0.f);
  #pragma unroll 4
  for (int c = g; c < NC; c += 16) {
    const float4 v4 = *reinterpret_cast<const float4*>(pbase + (size_t)c * T_OUT);
    const __half2* h = reinterpret_cast<const __half2*>(&v4);
    #pragma unroll
    for (int i = 0; i < 4; ++i) {
      const float2 f = __half22float2(h[i]);
      s2[i] += (f32x2){f.x, f.y};          // v_pk_add_f32
    }
  }
  #pragma unroll
  for (int i = 0; i < 4; ++i) {
    red[g][col][2 * i]     = s2[i].x;
    red[g][col][2 * i + 1] = s2[i].y;
  }
  __syncthreads();

  if (tid < 16) {
    f32x2 o2[4];
    #pragma unroll
    for (int i = 0; i < 4; ++i) o2[i] = (f32x2)(0.f);
    #pragma unroll
    for (int g2 = 0; g2 < 16; ++g2) {
      #pragma unroll
      for (int i = 0; i < 4; ++i)
        o2[i] += (f32x2){red[g2][tid][2 * i], red[g2][tid][2 * i + 1]};
    }
    const int cb2 = (bx & 63) * 16 + tid;
    float* po = out + (size_t)b * T_OUT + (size_t)cb2 * 8;
    reinterpret_cast<float4*>(po)[0] = make_float4(o2[0].x, o2[0].y, o2[1].x, o2[1].y);
    reinterpret_cast<float4*>(po)[1] = make_float4(o2[2].x, o2[2].y, o2[3].x, o2[3].y);
  }
}

extern "C" void kernel_launch(void* const* d_in, const int* in_sizes, int n_in,
                              void* d_out, int out_size, void* d_ws, size_t ws_size,
                              hipStream_t stream) {
  const float* freq  = (const float*)d_in[0];
  const float* ampp  = (const float*)d_in[1];
  const float* initp = (const float*)d_in[2];
  float* out = (float*)d_out;

  const size_t need = (size_t)BATCH * NC * T_OUT * sizeof(__half);  // 8.2 MB

  if (ws_size >= need) {
    __half* partial = (__half*)d_ws;
    synth<false><<<dim3(BATCH * NC), dim3(1024), 0, stream>>>(
        freq, ampp, initp, partial, nullptr);
    reduce_out<<<dim3(256), dim3(256), 0, stream>>>(partial, out);
  } else {
    hipMemsetAsync(d_out, 0, (size_t)out_size * sizeof(float), stream);
    synth<true><<<dim3(BATCH * NC), dim3(1024), 0, stream>>>(
        freq, ampp, initp, nullptr, out);
  }
}

// Round 11
// 24.395 us; speedup vs baseline: 3.6148x; 3.6148x over previous
//
#include <hip/hip_runtime.h>
#include <hip/hip_fp16.h>

// SineSynth: B=4, S=1000 sines, F=256 frames, 32x linear upsample -> T=8192.
// out[b][t] = sum_s amp_up[b,s,t] * sin( cumsum(freq_up*2pi/FS)[t] + init[b,s] )
//
// Closed-form phase (REVOLUTIONS -> v_fract feeds v_sin_f32):
//   t = 32k+16+j:  base(k) = 16*(C[k]+C[k+1])/FS + init/2pi,  C[k]=sum_{m<k} f[m]
//   p(j) = base + c1*(j+1) + c2*(j+1)^2,  c1=f[k]/FS, c2=(f[k+1]-f[k])/(64 FS)
//   am(j) = fma(d1, j+1, a0'),  d1=(a[k+1]-a[k])/32, a0'=a[k]-d1/2
//   head t<16: virtual coef column 256; tail k=255: kA1=kA => c2=d1=0
//
// R10 probe: compute is VALU/trans-bound at only ~1 block/CU resident
// (LDS 41.5KB blocked 2x residency). This round: 512-thr blocks, CH=4,
// NC=250 -> 1000 blocks, LDS 20.7KB -> 3-4 blocks/CU (true 6-8 waves/SIMD).
// Thread owns (k, half): 16 samples; k=255 half0=tail, half1=head(col 256).
// Two kernels (fence-fusion catastrophic on CDNA4 — R7).

#define FS_D 44100.0
#define S_TOTAL 1000
#define FRAMES 256
#define T_OUT 8192
#define BATCH 4
#define CH 4
#define NC 250      // CH*NC = S_TOTAL

typedef float f32x2 __attribute__((ext_vector_type(2)));

template <bool ATOMIC>
__global__ __launch_bounds__(512, 8) void synth(
    const float* __restrict__ freq, const float* __restrict__ amp,
    const float* __restrict__ initp, __half* __restrict__ pdst,
    float* __restrict__ odst)
{
  __shared__ float4 coef_lds[CH][FRAMES + 1];  // (c1,c2,d1,a0p); col 256 = head
  __shared__ float  base_lds[CH][FRAMES + 4];  // col 256 = head frac

  const int bx    = blockIdx.x;
  const int b     = bx / NC;
  const int chunk = bx % NC;
  const int s0    = chunk * CH;
  const int tid   = threadIdx.x;
  const int lane  = tid & 63;
  const int w     = tid >> 6;      // 0..7

  const float invfs = (float)(1.0 / FS_D);

  // ---- stage coefficients: 2 sweeps x 512 thr = 4 rows x 256 k ----
  #pragma unroll
  for (int rr = 0; rr < 2; ++rr) {
    const int slot = rr * 512 + tid;
    const int r  = slot >> 8;            // 0..3
    const int kA = slot & 255;
    const int kA1 = (kA < FRAMES - 1) ? kA + 1 : kA;   // tail clamp: c2=d1=0
    const long long roff = (long long)(b * S_TOTAL + s0 + r) * FRAMES;
    const float fA  = freq[roff + kA];
    const float fA1 = freq[roff + kA1];
    const float aA  = amp[roff + kA];
    const float aA1 = amp[roff + kA1];
    const float c1  = fA * invfs;
    const float c2  = (fA1 - fA) * (invfs * (1.0f / 64.0f));
    const float d1  = (aA1 - aA) * (1.0f / 32.0f);
    const float a0p = fmaf(-0.5f, d1, aA);
    coef_lds[r][kA] = make_float4(c1, c2, d1, a0p);
    if (kA == 0) coef_lds[r][FRAMES] = make_float4(c1, 0.f, 0.f, aA);  // head
  }

  // ---- per-row exclusive scan (double), waves 0..3, one row each ----
  if (w < CH) {
    const int r = w;
    const double inv2pi = 0.15915494309189535;
    const double k16    = 16.0 / FS_D;
    const long long roff = (long long)(b * S_TOTAL + s0 + r) * FRAMES;
    const float4 fv = reinterpret_cast<const float4*>(freq + roff)[lane];
    const double f0 = fv.x, f1 = fv.y, f2 = fv.z, f3 = fv.w;
    const double tot = f0 + f1 + f2 + f3;
    double incl = tot;
    #pragma unroll
    for (int off = 1; off < 64; off <<= 1) {
      double v = __shfl_up(incl, (unsigned)off, 64);
      if (lane >= off) incl += v;
    }
    double C = incl - tot;  // exclusive prefix of frames at 4*lane
    const double initrev = (double)initp[b * S_TOTAL + s0 + r] * inv2pi;
    if (lane == 0) base_lds[r][FRAMES] = (float)(initrev - floor(initrev));
    const double fk[4] = {f0, f1, f2, f3};
    float4 bw;
    #pragma unroll
    for (int i = 0; i < 4; ++i) {
      const double basev = k16 * (2.0 * C + fk[i]) + initrev;
      (&bw.x)[i] = (float)(basev - floor(basev));
      C += fk[i];
    }
    *reinterpret_cast<float4*>(&base_lds[r][4 * lane]) = bw;  // aligned b128
  }
  __syncthreads();

  // ---- synth: thread = (k=(w>>1)*64+lane, half h2=w&1), 16 samples ----
  const int h2 = w & 1;
  const int kk = (w >> 1) * 64 + lane;     // 0..255
  const bool hd = (kk == FRAMES - 1) && (h2 == 1);   // head t=0..15
  const int kidx = hd ? FRAMES : kk;
  const int j0 = hd ? 0 : h2 * 16;
  const int t0 = hd ? 0 : (kk * 32 + 16 + j0);

  f32x2 u2[8];
  const float u0f = (float)(j0 + 1);
  #pragma unroll
  for (int h = 0; h < 8; ++h)
    u2[h] = (f32x2){u0f + (float)(2 * h), u0f + (float)(2 * h + 1)};

  f32x2 acc2[8];
  #pragma unroll
  for (int h = 0; h < 8; ++h) acc2[h] = (f32x2)(0.f);

  #pragma unroll
  for (int r = 0; r < CH; ++r) {
    const float4 cf = coef_lds[r][kidx];
    const float  bs = base_lds[r][kidx];
    const f32x2 c1v = (f32x2)(cf.x);
    const f32x2 c2v = (f32x2)(cf.y);
    const f32x2 d1v = (f32x2)(cf.z);
    const f32x2 a0v = (f32x2)(cf.w);
    const f32x2 bsv = (f32x2)(bs);
    #pragma unroll
    for (int h = 0; h < 8; ++h) {
      const f32x2 t  = __builtin_elementwise_fma(c2v, u2[h], c1v);   // pk_fma
      const f32x2 p2 = __builtin_elementwise_fma(t, u2[h], bsv);     // pk_fma
      const f32x2 am = __builtin_elementwise_fma(d1v, u2[h], a0v);   // pk_fma
      f32x2 s2;
      s2.x = __builtin_amdgcn_sinf(__builtin_amdgcn_fractf(p2.x));
      s2.y = __builtin_amdgcn_sinf(__builtin_amdgcn_fractf(p2.y));
      acc2[h] = __builtin_elementwise_fma(am, s2, acc2[h]);          // pk_fma
    }
  }

  // ---- write-out: 16 halves = 32B at t0 (32B aligned) ----
  if (ATOMIC) {
    float* outb = odst + (long long)b * T_OUT + t0;
    #pragma unroll
    for (int h = 0; h < 8; ++h) {
      atomicAdd(outb + 2 * h,     acc2[h].x);
      atomicAdd(outb + 2 * h + 1, acc2[h].y);
    }
  } else {
    __half* pout = pdst + (size_t)(b * NC + chunk) * T_OUT + t0;
    union { float4 f; __half2 h[4]; } u0, u1;
    u0.h[0] = __floats2half2_rn(acc2[0].x, acc2[0].y);
    u0.h[1] = __floats2half2_rn(acc2[1].x, acc2[1].y);
    u0.h[2] = __floats2half2_rn(acc2[2].x, acc2[2].y);
    u0.h[3] = __floats2half2_rn(acc2[3].x, acc2[3].y);
    u1.h[0] = __floats2half2_rn(acc2[4].x, acc2[4].y);
    u1.h[1] = __floats2half2_rn(acc2[5].x, acc2[5].y);
    u1.h[2] = __floats2half2_rn(acc2[6].x, acc2[6].y);
    u1.h[3] = __floats2half2_rn(acc2[7].x, acc2[7].y);
    reinterpret_cast<float4*>(pout)[0] = u0.f;
    reinterpret_cast<float4*>(pout)[1] = u1.f;
  }
}

// Reduce: 256 blocks x 256 thr. Column = 8 output samples (16B of fp16).
// 1024 columns/batch; 16 cols/block x 16 chunk-groups. float4 loads,
// packed f32 accumulation. NC=250 -> ~16 iters/thread.
__global__ __launch_bounds__(256) void reduce_out(
    const __half* __restrict__ partial, float* __restrict__ out)
{
  __shared__ float red[16][16][8];
  const int tid = threadIdx.x;
  const int col = tid & 15;               // 0..15 within block
  const int g   = tid >> 4;               // 0..15 chunk-group
  const int bx  = blockIdx.x;             // 0..255
  const int b   = bx >> 6;                // 64 blocks per batch
  const int cb  = (bx & 63) * 16 + col;   // column in batch, 0..1023
  const __half* pbase = partial + (size_t)b * NC * T_OUT + (size_t)cb * 8;

  f32x2 s2[4];
  #pragma unroll
  for (int i = 0; i < 4; ++i) s2[i] = (f32x2)(0.f);
  #pragma unroll 4
  for (int c = g; c < NC; c += 16) {
    const float4 v4 = *reinterpret_cast<const float4*>(pbase + (size_t)c * T_OUT);
    const __half2* h = reinterpret_cast<const __half2*>(&v4);
    #pragma unroll
    for (int i = 0; i < 4; ++i) {
      const float2 f = __half22float2(h[i]);
      s2[i] += (f32x2){f.x, f.y};          // v_pk_add_f32
    }
  }
  #pragma unroll
  for (int i = 0; i < 4; ++i) {
    red[g][col][2 * i]     = s2[i].x;
    red[g][col][2 * i + 1] = s2[i].y;
  }
  __syncthreads();

  if (tid < 16) {
    f32x2 o2[4];
    #pragma unroll
    for (int i = 0; i < 4; ++i) o2[i] = (f32x2)(0.f);
    #pragma unroll
    for (int g2 = 0; g2 < 16; ++g2) {
      #pragma unroll
      for (int i = 0; i < 4; ++i)
        o2[i] += (f32x2){red[g2][tid][2 * i], red[g2][tid][2 * i + 1]};
    }
    const int cb2 = (bx & 63) * 16 + tid;
    float* po = out + (size_t)b * T_OUT + (size_t)cb2 * 8;
    reinterpret_cast<float4*>(po)[0] = make_float4(o2[0].x, o2[0].y, o2[1].x, o2[1].y);
    reinterpret_cast<float4*>(po)[1] = make_float4(o2[2].x, o2[2].y, o2[3].x, o2[3].y);
  }
}

extern "C" void kernel_launch(void* const* d_in, const int* in_sizes, int n_in,
                              void* d_out, int out_size, void* d_ws, size_t ws_size,
                              hipStream_t stream) {
  const float* freq  = (const float*)d_in[0];
  const float* ampp  = (const float*)d_in[1];
  const float* initp = (const float*)d_in[2];
  float* out = (float*)d_out;

  const size_t need = (size_t)BATCH * NC * T_OUT * sizeof(__half);  // 16.4 MB

  if (ws_size >= need) {
    __half* partial = (__half*)d_ws;
    synth<false><<<dim3(BATCH * NC), dim3(512), 0, stream>>>(
        freq, ampp, initp, partial, nullptr);
    reduce_out<<<dim3(256), dim3(256), 0, stream>>>(partial, out);
  } else {
    hipMemsetAsync(d_out, 0, (size_t)out_size * sizeof(float), stream);
    synth<true><<<dim3(BATCH * NC), dim3(512), 0, stream>>>(
        freq, ampp, initp, nullptr, out);
  }
}

// Round 12
// 20.106 us; speedup vs baseline: 4.3860x; 1.2133x over previous
//
#include <hip/hip_runtime.h>
#include <hip/hip_fp16.h>

// SineSynth: B=4, S=1000 sines, F=256 frames, 32x linear upsample -> T=8192.
// out[b][t] = sum_s amp_up[b,s,t] * sin( cumsum(freq_up*2pi/FS)[t] + init[b,s] )
//
// Closed-form phase (REVOLUTIONS -> v_fract feeds v_sin_f32):
//   t = 32k+16+j:  base(k) = 16*(C[k]+C[k+1])/FS + init/2pi,  C[k]=sum_{m<k} f[m]
//   p(j) = base + c1*(j+1) + c2*(j+1)^2,  c1=f[k]/FS, c2=(f[k+1]-f[k])/(64 FS)
//   am(j) = fma(d1, j+1, a0'),  d1=(a[k+1]-a[k])/32, a0'=a[k]-d1/2
//   head t<16: virtual coef column 256; tail k=255: kA1=kA => c2=d1=0
//
// PROVEN BEST (R9, 20.42us). Two kernels: synth 500x1024 (2 blocks/CU = 32
// waves/CU = full residency; VGPR 28, LDS 41.5KB), reduce 256x256.
// Fence-fusion catastrophic on CDNA4 (R7); cooperative launch unsupported
// (R6); 16-samples/thread spills at launch_bounds(512,8) (R11).

#define FS_D 44100.0
#define S_TOTAL 1000
#define FRAMES 256
#define T_OUT 8192
#define BATCH 4
#define CH 8
#define NC 125      // CH*NC = S_TOTAL

typedef float f32x2 __attribute__((ext_vector_type(2)));

template <bool ATOMIC>
__global__ __launch_bounds__(1024, 8) void synth(
    const float* __restrict__ freq, const float* __restrict__ amp,
    const float* __restrict__ initp, __half* __restrict__ pdst,
    float* __restrict__ odst)
{
  __shared__ float4 coef_lds[CH][FRAMES + 1];  // (c1,c2,d1,a0p); col 256 = head
  __shared__ float  base_lds[CH][FRAMES + 4];  // col 256 = head frac

  const int bx    = blockIdx.x;
  const int b     = bx / NC;
  const int chunk = bx % NC;
  const int s0    = chunk * CH;
  const int tid   = threadIdx.x;
  const int lane  = tid & 63;
  const int w     = tid >> 6;      // 0..15

  const float invfs = (float)(1.0 / FS_D);

  // ---- stage coefficients (16 waves x 2 sweeps = 8 rows x 256 k) ----
  #pragma unroll
  for (int rr = 0; rr < 2; ++rr) {
    const int r  = rr * 4 + (w >> 2);
    const int kA = (w & 3) * 64 + lane;
    const int kA1 = (kA < FRAMES - 1) ? kA + 1 : kA;   // tail clamp: c2=d1=0
    const long long roff = (long long)(b * S_TOTAL + s0 + r) * FRAMES;
    const float fA  = freq[roff + kA];
    const float fA1 = freq[roff + kA1];
    const float aA  = amp[roff + kA];
    const float aA1 = amp[roff + kA1];
    const float c1  = fA * invfs;
    const float c2  = (fA1 - fA) * (invfs * (1.0f / 64.0f));
    const float d1  = (aA1 - aA) * (1.0f / 32.0f);
    const float a0p = fmaf(-0.5f, d1, aA);
    coef_lds[r][kA] = make_float4(c1, c2, d1, a0p);
    if (kA == 0) coef_lds[r][FRAMES] = make_float4(c1, 0.f, 0.f, aA);  // head
  }

  // ---- per-row exclusive scan (double), waves 0..7, one row each ----
  if (w < 8) {
    const int r = w;
    const double inv2pi = 0.15915494309189535;
    const double k16    = 16.0 / FS_D;
    const long long roff = (long long)(b * S_TOTAL + s0 + r) * FRAMES;
    const float4 fv = reinterpret_cast<const float4*>(freq + roff)[lane];
    const double f0 = fv.x, f1 = fv.y, f2 = fv.z, f3 = fv.w;
    const double tot = f0 + f1 + f2 + f3;
    double incl = tot;
    #pragma unroll
    for (int off = 1; off < 64; off <<= 1) {
      double v = __shfl_up(incl, (unsigned)off, 64);
      if (lane >= off) incl += v;
    }
    double C = incl - tot;  // exclusive prefix of frames at 4*lane
    const double initrev = (double)initp[b * S_TOTAL + s0 + r] * inv2pi;
    if (lane == 0) base_lds[r][FRAMES] = (float)(initrev - floor(initrev));
    const double fk[4] = {f0, f1, f2, f3};
    float4 bw;
    #pragma unroll
    for (int i = 0; i < 4; ++i) {
      const double basev = k16 * (2.0 * C + fk[i]) + initrev;
      (&bw.x)[i] = (float)(basev - floor(basev));
      C += fk[i];
    }
    *reinterpret_cast<float4*>(&base_lds[r][4 * lane]) = bw;  // aligned b128
  }
  __syncthreads();

  // ---- synth: thread = (k=(w>>2)*64+lane, quarter q=w&3), 8 samples ----
  const int q = w & 3;
  const int k = (w >> 2) * 64 + lane;      // 0..255
  const bool hd = (k == FRAMES - 1) && (q >= 2);   // head t=0..15
  const int kidx = hd ? FRAMES : k;
  const int qq = hd ? (q - 2) : q;
  const int j0 = qq * 8;
  const int t0 = hd ? j0 : (k * 32 + 16 + j0);

  f32x2 u2[4];
  const float u0f = (float)(j0 + 1);
  #pragma unroll
  for (int h = 0; h < 4; ++h)
    u2[h] = (f32x2){u0f + (float)(2 * h), u0f + (float)(2 * h + 1)};

  f32x2 acc2[4];
  #pragma unroll
  for (int h = 0; h < 4; ++h) acc2[h] = (f32x2)(0.f);

  #pragma unroll
  for (int r = 0; r < CH; ++r) {
    const float4 cf = coef_lds[r][kidx];
    const float  bs = base_lds[r][kidx];
    const f32x2 c1v = (f32x2)(cf.x);
    const f32x2 c2v = (f32x2)(cf.y);
    const f32x2 d1v = (f32x2)(cf.z);
    const f32x2 a0v = (f32x2)(cf.w);
    const f32x2 bsv = (f32x2)(bs);
    #pragma unroll
    for (int h = 0; h < 4; ++h) {
      const f32x2 t  = __builtin_elementwise_fma(c2v, u2[h], c1v);   // pk_fma
      const f32x2 p2 = __builtin_elementwise_fma(t, u2[h], bsv);     // pk_fma
      const f32x2 am = __builtin_elementwise_fma(d1v, u2[h], a0v);   // pk_fma
      f32x2 s2;
      s2.x = __builtin_amdgcn_sinf(__builtin_amdgcn_fractf(p2.x));
      s2.y = __builtin_amdgcn_sinf(__builtin_amdgcn_fractf(p2.y));
      acc2[h] = __builtin_elementwise_fma(am, s2, acc2[h]);          // pk_fma
    }
  }

  // ---- write-out ----
  if (ATOMIC) {
    float* outb = odst + (long long)b * T_OUT + t0;
    #pragma unroll
    for (int h = 0; h < 4; ++h) {
      atomicAdd(outb + 2 * h,     acc2[h].x);
      atomicAdd(outb + 2 * h + 1, acc2[h].y);
    }
  } else {
    __half* pout = pdst + (size_t)(b * NC + chunk) * T_OUT + t0;
    union { float4 f; __half2 h[4]; } u;
    u.h[0] = __floats2half2_rn(acc2[0].x, acc2[0].y);
    u.h[1] = __floats2half2_rn(acc2[1].x, acc2[1].y);
    u.h[2] = __floats2half2_rn(acc2[2].x, acc2[2].y);
    u.h[3] = __floats2half2_rn(acc2[3].x, acc2[3].y);
    *reinterpret_cast<float4*>(pout) = u.f;
  }
}

// Reduce: 256 blocks x 256 thr. Column = 8 output samples (16B of fp16).
// 1024 columns/batch; 16 cols/block x 16 chunk-groups. float4 loads,
// packed f32 accumulation.
__global__ __launch_bounds__(256) void reduce_out(
    const __half* __restrict__ partial, float* __restrict__ out)
{
  __shared__ float red[16][16][8];
  const int tid = threadIdx.x;
  const int col = tid & 15;               // 0..15 within block
  const int g   = tid >> 4;               // 0..15 chunk-group
  const int bx  = blockIdx.x;             // 0..255
  const int b   = bx >> 6;                // 64 blocks per batch
  const int cb  = (bx & 63) * 16 + col;   // column in batch, 0..1023
  const __half* pbase = partial + (size_t)b * NC * T_OUT + (size_t)cb * 8;

  f32x2 s2[4];
  #pragma unroll
  for (int i = 0; i < 4; ++i) s2[i] = (f32x2)(0.f);
  #pragma unroll 4
  for (int c = g; c < NC; c += 16) {
    const float4 v4 = *reinterpret_cast<const float4*>(pbase + (size_t)c * T_OUT);
    const __half2* h = reinterpret_cast<const __half2*>(&v4);
    #pragma unroll
    for (int i = 0; i < 4; ++i) {
      const float2 f = __half22float2(h[i]);
      s2[i] += (f32x2){f.x, f.y};          // v_pk_add_f32
    }
  }
  #pragma unroll
  for (int i = 0; i < 4; ++i) {
    red[g][col][2 * i]     = s2[i].x;
    red[g][col][2 * i + 1] = s2[i].y;
  }
  __syncthreads();

  if (tid < 16) {
    f32x2 o2[4];
    #pragma unroll
    for (int i = 0; i < 4; ++i) o2[i] = (f32x2)(0.f);
    #pragma unroll
    for (int g2 = 0; g2 < 16; ++g2) {
      #pragma unroll
      for (int i = 0; i < 4; ++i)
        o2[i] += (f32x2){red[g2][tid][2 * i], red[g2][tid][2 * i + 1]};
    }
    const int cb2 = (bx & 63) * 16 + tid;
    float* po = out + (size_t)b * T_OUT + (size_t)cb2 * 8;
    reinterpret_cast<float4*>(po)[0] = make_float4(o2[0].x, o2[0].y, o2[1].x, o2[1].y);
    reinterpret_cast<float4*>(po)[1] = make_float4(o2[2].x, o2[2].y, o2[3].x, o2[3].y);
  }
}

extern "C" void kernel_launch(void* const* d_in, const int* in_sizes, int n_in,
                              void* d_out, int out_size, void* d_ws, size_t ws_size,
                              hipStream_t stream) {
  const float* freq  = (const float*)d_in[0];
  const float* ampp  = (const float*)d_in[1];
  const float* initp = (const float*)d_in[2];
  float* out = (float*)d_out;

  const size_t need = (size_t)BATCH * NC * T_OUT * sizeof(__half);  // 8.2 MB

  if (ws_size >= need) {
    __half* partial = (__half*)d_ws;
    synth<false><<<dim3(BATCH * NC), dim3(1024), 0, stream>>>(
        freq, ampp, initp, partial, nullptr);
    reduce_out<<<dim3(256), dim3(256), 0, stream>>>(partial, out);
  } else {
    hipMemsetAsync(d_out, 0, (size_t)out_size * sizeof(float), stream);
    synth<true><<<dim3(BATCH * NC), dim3(1024), 0, stream>>>(
        freq, ampp, initp, nullptr, out);
  }
}